// Round 1
// baseline (50.370 us; speedup 1.0000x reference)
//
#include <hip/hip_runtime.h>

#define DS   256    // downsampled dim (2048/8)
#define FULL 2048
#define NIMG 8

// Segment-mean contribution along one line of length 256.
// x: this thread's value, z: boundary flag, j: position in line.
// Returns lr+rl (or 2x where invalid), matching the reference _seg_means.
__device__ __forceinline__ float seg_contrib(float x, bool z, int j,
                                             float* s_cs, int* s_prev, int* s_nxt) {
    s_cs[j]   = x;
    s_prev[j] = z ? j : -1;
    s_nxt[j]  = z ? j : DS;
    __syncthreads();
    // Hillis-Steele: inclusive cumsum, inclusive max-scan, reverse inclusive min-scan
    for (int off = 1; off < DS; off <<= 1) {
        float a = (j >= off)      ? s_cs[j - off]   : 0.0f;
        int   p = (j >= off)      ? s_prev[j - off] : -1;
        int   q = (j + off < DS)  ? s_nxt[j + off]  : DS;
        __syncthreads();
        s_cs[j] += a;
        if (p > s_prev[j]) s_prev[j] = p;
        if (q < s_nxt[j])  s_nxt[j]  = q;
        __syncthreads();
    }
    int prev = (j > 0)      ? s_prev[j - 1] : -1;   // last boundary strictly before j
    int nxt  = (j < DS - 1) ? s_nxt[j + 1]  : DS;   // first boundary strictly after j
    bool valid = (!z) && (prev >= 0) && (nxt < DS);
    if (valid) {
        float sum_lr = s_cs[j]   - (prev > 0 ? s_cs[prev - 1] : 0.0f); // sum x[prev..j]
        float sum_rl = s_cs[nxt] - (j > 0    ? s_cs[j - 1]    : 0.0f); // sum x[j..nxt]
        return sum_lr / (float)(j - prev + 1) + sum_rl / (float)(nxt - j + 1);
    }
    return 2.0f * x;
}

// K1: gather downsampled values + horizontal segment means.
__global__ __launch_bounds__(256) void k_horiz(const float* __restrict__ x0,
                                               const int* __restrict__ x1,
                                               float* __restrict__ xd,
                                               unsigned char* __restrict__ zd,
                                               float* __restrict__ yH) {
    __shared__ float s_cs[DS];
    __shared__ int   s_prev[DS];
    __shared__ int   s_nxt[DS];
    int n = blockIdx.x >> 8;
    int i = blockIdx.x & 255;
    int j = threadIdx.x;
    size_t src = (((size_t)n * FULL) + (size_t)i * 8) * FULL + (size_t)j * 8;
    float x = x0[src];
    bool  z = (x1[src] == 0);
    int d = (n << 16) + (i << 8) + j;
    xd[d] = x;
    zd[d] = z ? 1 : 0;
    yH[d] = seg_contrib(x, z, j, s_cs, s_prev, s_nxt);
}

// K2: vertical segment means on compact arrays, accumulate in place.
__global__ __launch_bounds__(256) void k_vert(const float* __restrict__ xd,
                                              const unsigned char* __restrict__ zd,
                                              float* __restrict__ yH) {
    __shared__ float s_cs[DS];
    __shared__ int   s_prev[DS];
    __shared__ int   s_nxt[DS];
    int n = blockIdx.x >> 8;
    int c = blockIdx.x & 255;
    int t = threadIdx.x;
    int d = (n << 16) + (t << 8) + c;
    float x = xd[d];
    bool  z = (zd[d] != 0);
    float r = seg_contrib(x, z, t, s_cs, s_prev, s_nxt);
    yH[d] += r;
}

// K3: nearest-neighbor 8x8 upsample, coalesced float4 stores.
__global__ __launch_bounds__(256) void k_up(const float* __restrict__ yD,
                                            float* __restrict__ out) {
    int gid = blockIdx.x * blockDim.x + threadIdx.x;   // one float4 per thread
    int j4 = gid & 511;          // float4 index within a 2048-wide row
    int r  = gid >> 9;           // n*2048 + I (output row)
    int I  = r & 2047;
    int n  = r >> 11;
    int jd = j4 >> 1;            // downsampled column
    float v = yD[(n << 16) + ((I >> 3) << 8) + jd];
    ((float4*)out)[gid] = make_float4(v, v, v, v);
}

extern "C" void kernel_launch(void* const* d_in, const int* in_sizes, int n_in,
                              void* d_out, int out_size, void* d_ws, size_t ws_size,
                              hipStream_t stream) {
    const float* x0 = (const float*)d_in[0];
    const int*   x1 = (const int*)d_in[1];
    float* out = (float*)d_out;

    // workspace layout: xd (2MB) | yH (2MB) | zd (0.5MB)
    float* xd = (float*)d_ws;
    float* yH = xd + NIMG * DS * DS;
    unsigned char* zd = (unsigned char*)(yH + NIMG * DS * DS);

    dim3 blk(256);
    k_horiz<<<dim3(NIMG * DS), blk, 0, stream>>>(x0, x1, xd, zd, yH);
    k_vert <<<dim3(NIMG * DS), blk, 0, stream>>>(xd, zd, yH);
    // 8 imgs * 2048 rows * 512 float4 per row = 8388608 threads
    k_up   <<<dim3(32768), blk, 0, stream>>>(yH, out);
}